// Round 9
// baseline (50.012 us; speedup 1.0000x reference)
//
#include <hip/hip_runtime.h>

#define NPTS 32768
#define C 128
#define KNBR 16

typedef __attribute__((ext_vector_type(8))) short short8;
typedef __attribute__((ext_vector_type(4))) float floatx4;
typedef __attribute__((ext_vector_type(4))) int intx4;

__device__ __forceinline__ ushort f2b(float f) {
    union { float f; uint u; } x; x.f = f;
    uint r = (x.u + 0x7fffu + ((x.u >> 16) & 1u)) >> 16;
    return (ushort)r;
}
__device__ __forceinline__ ushort f2h(float f) {
    union { _Float16 h; ushort u; } x; x.h = (_Float16)f; return x.u;
}
__device__ __forceinline__ float h2f(ushort u) {
    union { ushort u; _Float16 h; } x; x.u = u; return (float)x.h;
}

// ---------------- LDS staging (XOR-swizzled): bf16 source / fp32 source (cast in-staging) --------
__device__ __forceinline__ void stage128_b(const ushort* __restrict__ gsrc, ushort* lds, int tid)
{
#pragma unroll
    for (int it = 0; it < 8; ++it) {
        const int f = it * 256 + tid;
        const int row = f >> 4, slot = f & 15;
        intx4 v = *(const intx4*)(gsrc + (size_t)f * 8);
        *(intx4*)(lds + ((row * 16 + (slot ^ (row & 7))) * 8)) = v;
    }
}
__device__ __forceinline__ void stage128_f(const float* __restrict__ gsrc, ushort* lds, int tid)
{
#pragma unroll
    for (int it = 0; it < 8; ++it) {
        const int f = it * 256 + tid;
        const int row = f >> 4, slot = f & 15;
        const float* s = gsrc + (size_t)f * 8;
        float4 v0 = *(const float4*)s;
        float4 v1 = *(const float4*)(s + 4);
        intx4 o;
        o.x = (int)((uint)f2b(v0.x) | ((uint)f2b(v0.y) << 16));
        o.y = (int)((uint)f2b(v0.z) | ((uint)f2b(v0.w) << 16));
        o.z = (int)((uint)f2b(v1.x) | ((uint)f2b(v1.y) << 16));
        o.w = (int)((uint)f2b(v1.z) | ((uint)f2b(v1.w) << 16));
        *(intx4*)(lds + ((row * 16 + (slot ^ (row & 7))) * 8)) = o;
    }
}

__device__ __forceinline__ void gemm_frag_acc(const ushort* ldsA, const ushort* ldsW,
                                              floatx4 acc[4][4], int lane)
{
    const int fr = lane & 15, kb = lane >> 4;
#pragma unroll
    for (int kk = 0; kk < 4; ++kk) {
        const int slot = kk * 4 + kb;
        short8 af[4], bf[4];
#pragma unroll
        for (int i = 0; i < 4; ++i) {
            const int row = i * 16 + fr;
            af[i] = *(const short8*)(ldsA + ((row * 16 + (slot ^ (row & 7))) * 8));
            bf[i] = *(const short8*)(ldsW + ((row * 16 + (slot ^ (row & 7))) * 8));
        }
#pragma unroll
        for (int i = 0; i < 4; ++i)
#pragma unroll
            for (int j = 0; j < 4; ++j)
                acc[i][j] = __builtin_amdgcn_mfma_f32_16x16x32_bf16(af[i], bf[j], acc[i][j], 0, 0, 0);
    }
}

// QKV: grid (NPTS/128, 3); fp32 inputs cast during staging (no prep kernel).
// sel=0 -> q8 + qscale; sel=1 -> kv8 k-half + scpack.lo; sel=2 -> kv8 v-half + scpack.hi
// int8 rows stored in col_of-permuted layout (head-pure 32B blocks).
__global__ __launch_bounds__(256) void qkv_gemm(
    const float* __restrict__ feats, const float* __restrict__ Wq,
    const float* __restrict__ Wk, const float* __restrict__ Wv,
    unsigned char* __restrict__ q8, unsigned char* __restrict__ kv8,
    ushort* __restrict__ scpack, float* __restrict__ qscale)
{
    __shared__ ushort ldsA[16384];
    __shared__ ushort ldsW[16384];
    __shared__ float rmax[2][128];
    const int tid = threadIdx.x, lane = tid & 63, wid = tid >> 6;
    const int r0 = blockIdx.x * 128, sel = blockIdx.y;
    const float* W = (sel == 0) ? Wq : (sel == 1) ? Wk : Wv;

    stage128_f(feats + (size_t)r0 * 128, ldsA, tid);
    stage128_f(W, ldsW, tid);
    __syncthreads();

    floatx4 acc[4][4];
#pragma unroll
    for (int i = 0; i < 4; ++i)
#pragma unroll
        for (int j = 0; j < 4; ++j) acc[i][j] = (floatx4){0.f, 0.f, 0.f, 0.f};

    const int wr = (wid >> 1) * 64, wc = (wid & 1) * 64;
    gemm_frag_acc(ldsA + wr * 16 * 8, ldsW + wc * 16 * 8, acc, lane);

    const int fr = lane & 15, kb = lane >> 4;

    // per-row absmax over this wave's 64 cols
    float mx[4][4];
#pragma unroll
    for (int i = 0; i < 4; ++i)
#pragma unroll
        for (int r = 0; r < 4; ++r) {
            float m = fabsf(acc[i][0][r]);
            m = fmaxf(m, fabsf(acc[i][1][r]));
            m = fmaxf(m, fabsf(acc[i][2][r]));
            m = fmaxf(m, fabsf(acc[i][3][r]));
            m = fmaxf(m, __shfl_xor(m, 1));
            m = fmaxf(m, __shfl_xor(m, 2));
            m = fmaxf(m, __shfl_xor(m, 4));
            m = fmaxf(m, __shfl_xor(m, 8));
            mx[i][r] = m;
        }
    if (fr == 0) {
#pragma unroll
        for (int i = 0; i < 4; ++i)
#pragma unroll
            for (int r = 0; r < 4; ++r)
                rmax[wc >> 6][wr + i * 16 + kb * 4 + r] = mx[i][r];
    }
    __syncthreads();

    const int boff = ((wc >> 5) + (fr & 1)) * 32 + (fr >> 1) * 4;
#pragma unroll
    for (int i = 0; i < 4; ++i)
#pragma unroll
        for (int r = 0; r < 4; ++r) {
            const int lr = wr + i * 16 + kb * 4 + r;
            const int nn = r0 + lr;
            const float comb = fmaxf(fmaxf(rmax[0][lr], rmax[1][lr]), 1e-20f);
            const float qs = 127.f / comb;
            int b0 = __float2int_rn(acc[i][0][r] * qs);
            int b1 = __float2int_rn(acc[i][1][r] * qs);
            int b2 = __float2int_rn(acc[i][2][r] * qs);
            int b3 = __float2int_rn(acc[i][3][r] * qs);
            uint u_lo = (uint)(b0 & 0xff) | ((uint)(b1 & 0xff) << 8);
            uint u_hi = (uint)(b2 & 0xff) | ((uint)(b3 & 0xff) << 8);
            uint o_lo = __shfl_xor(u_lo, 1);
            uint o_hi = __shfl_xor(u_hi, 1);
            uint word = (fr & 1) ? (o_hi | (u_hi << 16)) : (u_lo | (o_lo << 16));
            if (sel == 0) {
                *(uint*)(q8 + (size_t)nn * 128 + boff) = word;
                if (fr == 0 && wc == 0) qscale[nn] = comb * (1.f / 127.f);
            } else if (sel == 1) {
                *(uint*)(kv8 + (size_t)nn * 256 + boff) = word;
                if (fr == 0 && wc == 0) scpack[(size_t)nn * 2] = f2h(comb * (1.f / 127.f));
            } else {
                *(uint*)(kv8 + (size_t)nn * 256 + 128 + boff) = word;
                if (fr == 0 && wc == 0) scpack[(size_t)nn * 2 + 1] = f2h(comb * (1.f / 127.f));
            }
        }
}

// ---------------- attention: 1 wave/point, lane = (neighbor kk = l>>2, head h = l&3) ------------
// Output now stored in NORMAL channel order: lane l's two v-bytes are channels
// c0 = 32*(l>>4) + (l&15) and c0+16  (two contiguous 32B runs per 16-lane group).
__global__ __launch_bounds__(256, 6) void attn_kernel(
    const unsigned char* __restrict__ q8, const unsigned char* __restrict__ kv8,
    const ushort* __restrict__ scpack, const float* __restrict__ qscale,
    const int* __restrict__ knn, ushort* __restrict__ attn_p)
{
    const int tid = threadIdx.x;
    const int lane = tid & 63;
    const int wp = __builtin_amdgcn_readfirstlane(tid >> 6);
    const int n = blockIdx.x * 4 + wp;

    const int kk = lane >> 2, h = lane & 3;
    const int nb4 = knn[(size_t)n * KNBR + kk];
    const int* kr = knn + (size_t)n * KNBR;

    const unsigned char* krow = kv8 + (size_t)nb4 * 256 + h * 32;
    intx4 k0 = *(const intx4*)(krow);
    intx4 k1 = *(const intx4*)(krow + 16);
    const unsigned char* qrow = q8 + (size_t)n * 128 + h * 32;
    intx4 qq0 = *(const intx4*)(qrow);
    intx4 qq1 = *(const intx4*)(qrow + 16);
    const uint scp = *(const uint*)(scpack + (size_t)nb4 * 2);

    ushort vsh[KNBR];
#pragma unroll
    for (int j = 0; j < KNBR; ++j) {
        const int nbv = kr[j];
        vsh[j] = *(const ushort*)(kv8 + (size_t)nbv * 256 + 128 + lane * 2);
    }

    const float qs6 = qscale[n] * 0.17677669529663687f;

    int dp = 0;
#if __has_builtin(__builtin_amdgcn_sdot4)
#pragma unroll
    for (int i = 0; i < 4; ++i) dp = __builtin_amdgcn_sdot4(qq0[i], k0[i], dp, false);
#pragma unroll
    for (int i = 0; i < 4; ++i) dp = __builtin_amdgcn_sdot4(qq1[i], k1[i], dp, false);
#else
#pragma unroll
    for (int i = 0; i < 4; ++i) {
        uint a = (uint)qq0[i], b = (uint)k0[i];
        dp += (int)(signed char)(a) * (int)(signed char)(b)
            + (int)(signed char)(a >> 8) * (int)(signed char)(b >> 8)
            + (int)(signed char)(a >> 16) * (int)(signed char)(b >> 16)
            + (int)(signed char)(a >> 24) * (int)(signed char)(b >> 24);
        a = (uint)qq1[i]; b = (uint)k1[i];
        dp += (int)(signed char)(a) * (int)(signed char)(b)
            + (int)(signed char)(a >> 8) * (int)(signed char)(b >> 8)
            + (int)(signed char)(a >> 16) * (int)(signed char)(b >> 16)
            + (int)(signed char)(a >> 24) * (int)(signed char)(b >> 24);
    }
#endif

    const float ksc = h2f((ushort)(scp & 0xffff));
    const float vsc = h2f((ushort)(scp >> 16));
    const float sc = (float)dp * ksc * qs6;

    float mxv = sc;
    mxv = fmaxf(mxv, __shfl_xor(mxv, 4));
    mxv = fmaxf(mxv, __shfl_xor(mxv, 8));
    mxv = fmaxf(mxv, __shfl_xor(mxv, 16));
    mxv = fmaxf(mxv, __shfl_xor(mxv, 32));
    const float e = __expf(sc - mxv);
    float sm = e;
    sm += __shfl_xor(sm, 4);
    sm += __shfl_xor(sm, 8);
    sm += __shfl_xor(sm, 16);
    sm += __shfl_xor(sm, 32);
    const float wgt = e * vsc / sm;

    const int h2v = lane >> 4;
    float a0 = 0.f, a1 = 0.f;
#pragma unroll
    for (int j = 0; j < KNBR; ++j) {
        const float w2 = __shfl(wgt, j * 4 + h2v);
        const ushort u = vsh[j];
        a0 += w2 * (float)(signed char)(u & 0xff);
        a1 += w2 * (float)(signed char)(u >> 8);
    }
    // normal channel order: c0 = 32*(lane>>4) + (lane&15), c1 = c0 + 16
    const int cb = 32 * (lane >> 4) + (lane & 15);
    attn_p[(size_t)n * 128 + cb]      = f2b(a0);
    attn_p[(size_t)n * 128 + cb + 16] = f2b(a1);
}

// ---------------- output projection: plain layouts, Wo cast in-staging from fp32 ----------------
__global__ __launch_bounds__(256) void out_gemm(
    const ushort* __restrict__ A, const float* __restrict__ Wo,
    const float* __restrict__ bias, float* __restrict__ out)
{
    __shared__ ushort ldsA[16384];
    __shared__ ushort ldsW[16384];
    const int tid = threadIdx.x, lane = tid & 63, wid = tid >> 6;
    const int r0 = blockIdx.x * 128;

    stage128_b(A + (size_t)r0 * 128, ldsA, tid);
    stage128_f(Wo, ldsW, tid);
    __syncthreads();

    floatx4 acc[4][4];
#pragma unroll
    for (int i = 0; i < 4; ++i)
#pragma unroll
        for (int j = 0; j < 4; ++j) acc[i][j] = (floatx4){0.f, 0.f, 0.f, 0.f};

    const int wr = (wid >> 1) * 64, wc = (wid & 1) * 64;
    gemm_frag_acc(ldsA + wr * 16 * 8, ldsW + wc * 16 * 8, acc, lane);

    const int fr = lane & 15, kb = lane >> 4;
#pragma unroll
    for (int i = 0; i < 4; ++i)
#pragma unroll
        for (int j = 0; j < 4; ++j) {
            const int col = wc + j * 16 + fr;
            const float bv = bias[col];
#pragma unroll
            for (int r = 0; r < 4; ++r) {
                const int n = r0 + wr + i * 16 + kb * 4 + r;
                out[(size_t)n * 128 + col] = acc[i][j][r] + bv;
            }
        }
}

extern "C" void kernel_launch(void* const* d_in, const int* in_sizes, int n_in,
                              void* d_out, int out_size, void* d_ws, size_t ws_size,
                              hipStream_t stream)
{
    const float* feats = (const float*)d_in[0];
    const int*   knn   = (const int*)d_in[2];
    const float* Wq    = (const float*)d_in[3];
    const float* Wk    = (const float*)d_in[4];
    const float* Wv    = (const float*)d_in[5];
    const float* Wo    = (const float*)d_in[6];
    const float* bo    = (const float*)d_in[7];
    float* out = (float*)d_out;

    ushort* attn_p = (ushort*)d_ws;                                    // N*128 ushort
    unsigned char* q8  = (unsigned char*)(attn_p + (size_t)NPTS * C);  // N*128 B
    unsigned char* kv8 = q8 + (size_t)NPTS * 128;                      // N*256 B
    ushort* scpack = (ushort*)(kv8 + (size_t)NPTS * 256);              // N*2 ushort
    float* qscale  = (float*)(scpack + (size_t)NPTS * 2);              // N floats

    qkv_gemm<<<dim3(NPTS / 128, 3), 256, 0, stream>>>(feats, Wq, Wk, Wv,
                                                      q8, kv8, scpack, qscale);
    attn_kernel<<<NPTS / 4, 256, 0, stream>>>(q8, kv8, scpack, qscale, knn, attn_p);
    out_gemm<<<NPTS / 128, 256, 0, stream>>>(attn_p, Wo, bo, out);
}